// Round 3
// baseline (155.193 us; speedup 1.0000x reference)
//
#include <hip/hip_runtime.h>

#define NC 32
#define DC 16
#define LSEQ 2048

// ---------------------------------------------------------------------------
// No-spin forward chaining: blocks of batch b write partials, release-fence,
// atomicAdd ctr[b]; the LAST arriver (prev==15) folds partials and computes
// the caps step for b. No block ever waits on another block -> deadlock-free
// under ANY dispatch order / occupancy. Phase ordering across routing
// iterations comes from stream-ordered kernel launches.
// ---------------------------------------------------------------------------

// caps math, shared by folder tails:
//   s[n][d] = sum_i v[n][i] * W[i][n*16+d]   (v row stride VSTR floats)
//   o = s / sqrt(sum_d s^2 + 1e-7)
// thread t -> n = t>>2, d4 = t&3 (one float4 of d per thread).

// ---------------------------------------------------------------------------
// K1: per-chunk column sums of u; last arriver: fold -> v0 (uniform c = 1/32),
// caps0 -> wtil.
// ---------------------------------------------------------------------------
__global__ __launch_bounds__(128) void k_sum_caps0(const float* __restrict__ u,
                                                   const float* __restrict__ W,
                                                   float* __restrict__ v0p,
                                                   float* __restrict__ wtil,
                                                   int* __restrict__ ctr) {
    const int rid = blockIdx.x;
    const int b   = (rid & 7) + ((rid >> 7) << 3);   // b-groups share rid%8 (XCD)
    const int j   = (rid >> 3) & 15;
    const int gb  = b * 16 + j;
    const int t   = threadIdx.x;

    __shared__ float red[512];
    __shared__ float vS[64];
    __shared__ float oS[512];
    __shared__ int amLast;

    // ---- partial column sums over this chunk's 128 rows (coalesced) ----
    const float4* ug = (const float4*)(u + (b * LSEQ + j * 128) * 64);
    float4 a = {0.f, 0.f, 0.f, 0.f};
#pragma unroll
    for (int r = 0; r < 16; ++r) {
        float4 x = ug[t + 128 * r];
        a.x += x.x; a.y += x.y; a.z += x.z; a.w += x.w;
    }
    ((float4*)red)[t] = a;
    __syncthreads();
    if (t < 64) {
        float s = 0.f;
#pragma unroll
        for (int g = 0; g < 8; ++g) s += red[t + 64 * g];
        v0p[gb * 64 + t] = s;
    }
    __syncthreads();                       // drain stores before signaling
    if (t == 0) {
        __threadfence();                   // release (device scope)
        int prev = atomicAdd(&ctr[b * 32 + 0], 1);
        amLast = (prev == 15);
    }
    __syncthreads();
    if (!amLast) return;
    __threadfence();                       // acquire

    // ---- fold 16 chunk partials -> v0 (scaled by uniform c = 1/32) ----
    if (t < 64) {
        float s = 0.f;
#pragma unroll
        for (int ch = 0; ch < 16; ++ch) s += v0p[(b * 16 + ch) * 64 + t];
        vS[t] = s * (1.f / 32.f);
    }
    __syncthreads();

    // ---- caps0: same v for every n (uniform c) ----
    const int n = t >> 2, d4 = t & 3;
    const float4* W4 = (const float4*)W;
    float4 s4 = {0.f, 0.f, 0.f, 0.f};
#pragma unroll
    for (int i = 0; i < 64; ++i) {
        float vi = vS[i];
        float4 wv = W4[i * 128 + n * 4 + d4];
        s4.x = fmaf(vi, wv.x, s4.x);
        s4.y = fmaf(vi, wv.y, s4.y);
        s4.z = fmaf(vi, wv.z, s4.z);
        s4.w = fmaf(vi, wv.w, s4.w);
    }
    float s2 = s4.x * s4.x + s4.y * s4.y + s4.z * s4.z + s4.w * s4.w;
    s2 += __shfl_xor(s2, 1);
    s2 += __shfl_xor(s2, 2);
    float inv = 1.f / sqrtf(s2 + 1e-7f);
    float4 o4 = {s4.x * inv, s4.y * inv, s4.z * inv, s4.w * inv};
    ((float4*)oS)[t] = o4;                 // oS[n][d]
    __syncthreads();

    // ---- wtil[b][n][i] = sum_d W[i][n*16+d] * o[n][d] ----
    const float4* oS4 = (const float4*)oS;
#pragma unroll
    for (int rep = 0; rep < 16; ++rep) {
        int idx = t + 128 * rep;           // 0..2047: n = idx>>6, i = idx&63
        int nn = idx >> 6, ii = idx & 63;
        float acc = 0.f;
#pragma unroll
        for (int q = 0; q < 4; ++q) {
            float4 wv = W4[ii * 128 + nn * 4 + q];
            float4 ov = oS4[nn * 4 + q];
            acc += wv.x * ov.x + wv.y * ov.y + wv.z * ov.z + wv.w * ov.w;
        }
        wtil[b * (NC * 64) + idx] = acc;
    }
}

// ---------------------------------------------------------------------------
// K2/K3: route (verbatim round-0-verified algebra) + last-arriver fold+caps.
// PH selects the counter slot; FINAL writes out instead of wtil.
// ---------------------------------------------------------------------------
template <int PH, bool FINAL>
__global__ __launch_bounds__(128) void k_route_caps(const float* __restrict__ u,
                                                    const float* __restrict__ W,
                                                    const float* __restrict__ wtil_in,
                                                    float* __restrict__ wtil_out,
                                                    float* __restrict__ out,
                                                    float* __restrict__ vpart,
                                                    int* __restrict__ ctr) {
    const int rid  = blockIdx.x;
    const int b    = (rid & 7) + ((rid >> 7) << 3);
    const int j    = (rid >> 3) & 15;
    const int gb   = b * 16 + j;
    const int t    = threadIdx.x;
    const int w    = t >> 6;
    const int lane = t & 63;

    __shared__ float uS[128 * 68];     // u chunk, row stride 68 floats
    __shared__ float wS[32 * 68];      // wtil tile
    __shared__ float cS[2 * 2304];     // per-wave c / reductions / caps scratch
    __shared__ int amLast;
    float4* uS4 = (float4*)uS;
    float4* wS4 = (float4*)wS;
    float4* cS4 = (float4*)cS;
    float*  cw  = cS + w * 2304;
    float4* cw4 = (float4*)cw;

    // ---- stage u chunk and wtil tile ----
    const float4* ug = (const float4*)(u + (b * LSEQ + j * 128) * 64);
#pragma unroll
    for (int r = 0; r < 16; ++r) {
        int idx = t + 128 * r;
        uS4[(idx >> 4) * 17 + (idx & 15)] = ug[idx];
    }
    const float4* wg = (const float4*)(wtil_in + b * (NC * 64));
#pragma unroll
    for (int r = 0; r < 4; ++r) {
        int idx = t + 128 * r;
        wS4[(idx >> 4) * 17 + (idx & 15)] = wg[idx];
    }
    __syncthreads();

    // ---- phase A: per-lane 8l x 4n logits ----
    const int lr = lane & 7, lc = lane >> 3;
    float acc[8][4];
#pragma unroll
    for (int i = 0; i < 8; ++i)
#pragma unroll
        for (int jj = 0; jj < 4; ++jj) acc[i][jj] = 0.f;
    const int arow = w * 64 + lr;
#pragma unroll 4
    for (int k4 = 0; k4 < 16; ++k4) {
        float4 wf[4];
#pragma unroll
        for (int jj = 0; jj < 4; ++jj) wf[jj] = wS4[(lc * 4 + jj) * 17 + k4];
#pragma unroll
        for (int i = 0; i < 8; ++i) {
            float4 av = uS4[(arow + 8 * i) * 17 + k4];
#pragma unroll
            for (int jj = 0; jj < 4; ++jj) {
                acc[i][jj] = fmaf(av.x, wf[jj].x, acc[i][jj]);
                acc[i][jj] = fmaf(av.y, wf[jj].y, acc[i][jj]);
                acc[i][jj] = fmaf(av.z, wf[jj].z, acc[i][jj]);
                acc[i][jj] = fmaf(av.w, wf[jj].w, acc[i][jj]);
            }
        }
    }

    // ---- softmax over n per l-row ----
#pragma unroll
    for (int i = 0; i < 8; ++i) {
        float m = fmaxf(fmaxf(acc[i][0], acc[i][1]), fmaxf(acc[i][2], acc[i][3]));
        m = fmaxf(m, __shfl_xor(m, 8));
        m = fmaxf(m, __shfl_xor(m, 16));
        m = fmaxf(m, __shfl_xor(m, 32));
        float e0 = __expf(acc[i][0] - m), e1 = __expf(acc[i][1] - m);
        float e2 = __expf(acc[i][2] - m), e3 = __expf(acc[i][3] - m);
        float ss = e0 + e1 + e2 + e3;
        ss += __shfl_xor(ss, 8);
        ss += __shfl_xor(ss, 16);
        ss += __shfl_xor(ss, 32);
        float inv = 1.f / ss;
        float4 cvv = {e0 * inv, e1 * inv, e2 * inv, e3 * inv};
        cw4[(lr + 8 * i) * 9 + lc] = cvv;
    }
    __syncthreads();

    // ---- phase B: V[n][d] += sum_l c[l][n] * u[l][d] ----
    const int dr = lane & 7, ng = lane >> 3;
    float vacc[4][8];
#pragma unroll
    for (int jj = 0; jj < 4; ++jj)
#pragma unroll
        for (int k = 0; k < 8; ++k) vacc[jj][k] = 0.f;
#pragma unroll 8
    for (int lrel = 0; lrel < 64; ++lrel) {
        float4 cv = cw4[lrel * 9 + ng];
        const float4* ur = uS4 + (w * 64 + lrel) * 17 + dr * 2;
        float4 u0 = ur[0], u1 = ur[1];
        float* cp = (float*)&cv;
#pragma unroll
        for (int jj = 0; jj < 4; ++jj) {
            float c = cp[jj];
            vacc[jj][0] = fmaf(c, u0.x, vacc[jj][0]);
            vacc[jj][1] = fmaf(c, u0.y, vacc[jj][1]);
            vacc[jj][2] = fmaf(c, u0.z, vacc[jj][2]);
            vacc[jj][3] = fmaf(c, u0.w, vacc[jj][3]);
            vacc[jj][4] = fmaf(c, u1.x, vacc[jj][4]);
            vacc[jj][5] = fmaf(c, u1.y, vacc[jj][5]);
            vacc[jj][6] = fmaf(c, u1.z, vacc[jj][6]);
            vacc[jj][7] = fmaf(c, u1.w, vacc[jj][7]);
        }
    }
#pragma unroll
    for (int jj = 0; jj < 4; ++jj) {
        float* rp = cw + (ng * 4 + jj) * 64 + dr * 8;
        float4 r0 = {vacc[jj][0], vacc[jj][1], vacc[jj][2], vacc[jj][3]};
        float4 r1 = {vacc[jj][4], vacc[jj][5], vacc[jj][6], vacc[jj][7]};
        ((float4*)rp)[0] = r0;
        ((float4*)rp)[1] = r1;
    }
    __syncthreads();
    float4* vp4 = (float4*)(vpart + gb * 2048);
#pragma unroll
    for (int sft = 0; sft < 4; ++sft) {
        int idx4 = t + 128 * sft;
        float4 x = cS4[idx4];
        float4 y = cS4[576 + idx4];
        float4 o = {x.x + y.x, x.y + y.y, x.z + y.z, x.w + y.w};
        vp4[idx4] = o;
    }
    __syncthreads();                       // drain stores before signaling

    // ---- arrive; last block folds + does caps for this b ----
    if (t == 0) {
        __threadfence();                   // release
        int prev = atomicAdd(&ctr[b * 32 + PH], 1);
        amLast = (prev == 15);
    }
    __syncthreads();
    if (!amLast) return;
    __threadfence();                       // acquire

    // fold 16 chunk partials -> vS[32][68] (padded rows) in cS
    const float4* vpb = (const float4*)(vpart + b * 16 * 2048);
#pragma unroll
    for (int rep = 0; rep < 4; ++rep) {
        int idx4 = t + 128 * rep;          // 0..511: n = idx4>>4, c4 = idx4&15
        float4 s = {0.f, 0.f, 0.f, 0.f};
#pragma unroll
        for (int ch = 0; ch < 16; ++ch) {
            float4 x = vpb[ch * 512 + idx4];
            s.x += x.x; s.y += x.y; s.z += x.z; s.w += x.w;
        }
        cS4[(idx4 >> 4) * 17 + (idx4 & 15)] = s;
    }
    __syncthreads();

    // caps: s4 per (n = t>>2, d4 = t&3)
    const int n = t >> 2, d4 = t & 3;
    const float4* W4 = (const float4*)W;
    const float* vrow = &cS[n * 68];
    float4 s4 = {0.f, 0.f, 0.f, 0.f};
#pragma unroll
    for (int i = 0; i < 64; ++i) {
        float vi = vrow[i];
        float4 wv = W4[i * 128 + n * 4 + d4];
        s4.x = fmaf(vi, wv.x, s4.x);
        s4.y = fmaf(vi, wv.y, s4.y);
        s4.z = fmaf(vi, wv.z, s4.z);
        s4.w = fmaf(vi, wv.w, s4.w);
    }
    float s2 = s4.x * s4.x + s4.y * s4.y + s4.z * s4.z + s4.w * s4.w;
    s2 += __shfl_xor(s2, 1);
    s2 += __shfl_xor(s2, 2);
    float inv = 1.f / sqrtf(s2 + 1e-7f);
    float4 o4 = {s4.x * inv, s4.y * inv, s4.z * inv, s4.w * inv};

    if (FINAL) {
        ((float4*)out)[b * 128 + t] = o4;  // out[b][n][d], coalesced
        return;
    }
    float* oS = cS + 2304;                 // oS[32][16]
    ((float4*)oS)[t] = o4;
    __syncthreads();
    const float4* oS4 = (const float4*)oS;
#pragma unroll
    for (int rep = 0; rep < 16; ++rep) {
        int idx = t + 128 * rep;           // 0..2047: n = idx>>6, i = idx&63
        int nn = idx >> 6, ii = idx & 63;
        float a2 = 0.f;
#pragma unroll
        for (int q = 0; q < 4; ++q) {
            float4 wv = W4[ii * 128 + nn * 4 + q];
            float4 ov = oS4[nn * 4 + q];
            a2 += wv.x * ov.x + wv.y * ov.y + wv.z * ov.z + wv.w * ov.w;
        }
        wtil_out[b * (NC * 64) + idx] = a2;
    }
}

extern "C" void kernel_launch(void* const* d_in, const int* in_sizes, int n_in,
                              void* d_out, int out_size, void* d_ws, size_t ws_size,
                              hipStream_t stream) {
    const float* u = (const float*)d_in[0];  // [32, 2048, 64] f32
    const float* W = (const float*)d_in[1];  // [1, 64, 512]  f32
    float* out = (float*)d_out;              // [32, 32, 16]  f32
    float* ws  = (float*)d_ws;
    int*   ctr   = (int*)ws;                   // 32 b * 32 ints (128B spacing)
    float* v0p   = ws + 1024;                  // 512*64
    float* wt    = ws + 1024 + 16384;          // 32*32*64
    float* vpart = ws + 1024 + 16384 + 65536;  // 512*2048

    hipMemsetAsync(ctr, 0, 32 * 32 * sizeof(int), stream);

    k_sum_caps0<<<512, 128, 0, stream>>>(u, W, v0p, wt, ctr);
    k_route_caps<1, false><<<512, 128, 0, stream>>>(u, W, wt, wt, nullptr, vpart, ctr);
    k_route_caps<2, true ><<<512, 128, 0, stream>>>(u, W, wt, nullptr, out, vpart, ctr);
}

// Round 4
// 139.752 us; speedup vs baseline: 1.1105x; 1.1105x over previous
//
#include <hip/hip_runtime.h>

#define NC 32
#define DC 16
#define LSEQ 2048

// ---------------------------------------------------------------------------
// K0: column partial sums of u per 128-l chunk, atomicAdd into v0[b][64].
// grid 512 (b = bid>>4, j = bid&15), 256 threads. v0 zeroed by host memset.
// ---------------------------------------------------------------------------
__global__ __launch_bounds__(256) void k_sum(const float* __restrict__ u,
                                             float* __restrict__ v0) {
    const int b = blockIdx.x >> 4, j = blockIdx.x & 15;
    const int t = threadIdx.x;
    const int q = t & 15, r = t >> 4;
    const float4* ug = (const float4*)(u + (b * LSEQ + j * 128) * 64);
    float4 a = {0.f, 0.f, 0.f, 0.f};
#pragma unroll
    for (int g = 0; g < 8; ++g) {
        float4 x = ug[(r + 16 * g) * 16 + q];
        a.x += x.x; a.y += x.y; a.z += x.z; a.w += x.w;
    }
    __shared__ float red[16][64];
    red[r][q * 4 + 0] = a.x;
    red[r][q * 4 + 1] = a.y;
    red[r][q * 4 + 2] = a.z;
    red[r][q * 4 + 3] = a.w;
    __syncthreads();
    if (t < 64) {
        float s = 0.f;
#pragma unroll
        for (int rr = 0; rr < 16; ++rr) s += red[rr][t];
        atomicAdd(&v0[b * 64 + t], s);
    }
}

// ---------------------------------------------------------------------------
// caps head (512 threads): read folded v for batch b, s = v@W_n, L2-normalize,
// then either write o to out (FINAL) or write wtil rows into wS ([32][68] pad)
// for the route phase that follows. cSc: >= 2688 floats of LDS scratch.
// ITER0: v is the 64-float column sum (uniform c = 1/32 applied here).
// ---------------------------------------------------------------------------
template <int ITER0, int FINAL>
__device__ __forceinline__ void caps_head(int b, int t,
                                          const float* __restrict__ W,
                                          const float* __restrict__ vsrc,
                                          float* wS, float* outg, float* cSc) {
    float* vf = cSc;           // ITER0: [64]; else [32][68] padded
    float* oS = cSc + 2176;    // [512]
    if (ITER0) {
        if (t < 64) vf[t] = vsrc[b * 64 + t] * (1.f / 32.f);
    } else {
        float4 s = ((const float4*)(vsrc + b * 2048))[t];
        ((float4*)vf)[(t >> 4) * 17 + (t & 15)] = s;
    }
    __syncthreads();
    const int n = t >> 4, d = t & 15;
    const float* vrow = ITER0 ? vf : vf + n * 68;
    float s = 0.f;
#pragma unroll
    for (int i = 0; i < 64; ++i)
        s = fmaf(vrow[i], W[i * (NC * DC) + n * DC + d], s);
    float s2 = s * s;
    s2 += __shfl_xor(s2, 1);
    s2 += __shfl_xor(s2, 2);
    s2 += __shfl_xor(s2, 4);
    s2 += __shfl_xor(s2, 8);
    float o = s / sqrtf(s2 + 1e-7f);
    if (FINAL) {
        outg[b * (NC * DC) + t] = o;   // out[b][n][d], t = n*16+d, coalesced
        return;
    }
    oS[t] = o;
    __syncthreads();
    // wtil[n][i] = sum_d W[i][n*16+d] * o[n][d]  -> wS[n][i], row stride 68
    const float4* o4 = (const float4*)(oS + n * 16);
    float4 ov0 = o4[0], ov1 = o4[1], ov2 = o4[2], ov3 = o4[3];
    const int i4 = t & 15;
    float4 wv;
    float* wvp = (float*)&wv;
#pragma unroll
    for (int k = 0; k < 4; ++k) {
        const int i = i4 * 4 + k;
        const float4* wr = (const float4*)(W + i * (NC * DC) + n * DC);
        float4 w0 = wr[0], w1 = wr[1], w2 = wr[2], w3 = wr[3];
        float acc = w0.x * ov0.x + w0.y * ov0.y + w0.z * ov0.z + w0.w * ov0.w;
        acc += w1.x * ov1.x + w1.y * ov1.y + w1.z * ov1.z + w1.w * ov1.w;
        acc += w2.x * ov2.x + w2.y * ov2.y + w2.z * ov2.z + w2.w * ov2.w;
        acc += w3.x * ov3.x + w3.y * ov3.y + w3.z * ov3.z + w3.w * ov3.w;
        wvp[k] = acc;
    }
    ((float4*)wS)[n * 17 + i4] = wv;
}

// ---------------------------------------------------------------------------
// Route: grid 512 (b = rid>>4, j = rid&15), 512 threads = 8 waves (4/SIMD).
// Head: redundant per-block caps -> wS (LDS). Body: wave w owns l-rows
// [w*16, w*16+16); per-lane 2l x 4n logits tile, in-register softmax over n,
// per-lane 4n x 8d V-tile. Tail: 8->4->1 LDS fold, atomicAdd into vout[b].
// ---------------------------------------------------------------------------
template <int ITER0>
__global__ __launch_bounds__(512, 4) void k_route(const float* __restrict__ u,
                                                  const float* __restrict__ W,
                                                  const float* __restrict__ vin,
                                                  float* __restrict__ vout) {
    const int rid = blockIdx.x;
    const int b = rid >> 4, j = rid & 15;
    const int t = threadIdx.x;
    const int w = t >> 6, lane = t & 63;

    __shared__ float smem[15488];      // 61952 B -> 2 blocks/CU
    float* uS = smem;                  // [128][68]
    float* wS = smem + 8704;           // [32][68]
    float* cS = smem + 10880;          // [128][36] c; head scratch first
    float4* uS4 = (float4*)uS;
    float4* wS4 = (float4*)wS;
    float4* c4  = (float4*)cS;

    // issue u-tile loads early (latency hides under the caps head)
    const float4* ug = (const float4*)(u + (b * LSEQ + j * 128) * 64);
    float4 ur[4];
#pragma unroll
    for (int r = 0; r < 4; ++r) ur[r] = ug[t + 512 * r];

    caps_head<ITER0, 0>(b, t, W, vin, wS, nullptr, cS);

#pragma unroll
    for (int r = 0; r < 4; ++r) {
        int idx = t + 512 * r;
        uS4[(idx >> 4) * 17 + (idx & 15)] = ur[r];
    }
    __syncthreads();

    // ---- phase A: per-lane 2l x 4n logits ----
    const int lw = w * 16;
    const int lr = lane & 7, lc = lane >> 3;
    float acc[2][4];
#pragma unroll
    for (int i = 0; i < 2; ++i)
#pragma unroll
        for (int jj = 0; jj < 4; ++jj) acc[i][jj] = 0.f;
#pragma unroll 4
    for (int k4 = 0; k4 < 16; ++k4) {
        float4 wf[4];
#pragma unroll
        for (int jj = 0; jj < 4; ++jj) wf[jj] = wS4[(lc * 4 + jj) * 17 + k4];
#pragma unroll
        for (int i = 0; i < 2; ++i) {
            float4 av = uS4[(lw + lr + 8 * i) * 17 + k4];
#pragma unroll
            for (int jj = 0; jj < 4; ++jj) {
                acc[i][jj] = fmaf(av.x, wf[jj].x, acc[i][jj]);
                acc[i][jj] = fmaf(av.y, wf[jj].y, acc[i][jj]);
                acc[i][jj] = fmaf(av.z, wf[jj].z, acc[i][jj]);
                acc[i][jj] = fmaf(av.w, wf[jj].w, acc[i][jj]);
            }
        }
    }

    // ---- softmax over n per l-row, write c[l][36-stride] ----
#pragma unroll
    for (int i = 0; i < 2; ++i) {
        float m = fmaxf(fmaxf(acc[i][0], acc[i][1]), fmaxf(acc[i][2], acc[i][3]));
        m = fmaxf(m, __shfl_xor(m, 8));
        m = fmaxf(m, __shfl_xor(m, 16));
        m = fmaxf(m, __shfl_xor(m, 32));
        float e0 = __expf(acc[i][0] - m), e1 = __expf(acc[i][1] - m);
        float e2 = __expf(acc[i][2] - m), e3 = __expf(acc[i][3] - m);
        float ss = e0 + e1 + e2 + e3;
        ss += __shfl_xor(ss, 8);
        ss += __shfl_xor(ss, 16);
        ss += __shfl_xor(ss, 32);
        float inv = 1.f / ss;
        float4 cv = {e0 * inv, e1 * inv, e2 * inv, e3 * inv};
        c4[(lw + lr + 8 * i) * 9 + lc] = cv;
    }
    __syncthreads();

    // ---- phase B: per-lane 4n x 8d V-tile over this wave's 16 l's ----
    const int dr = lane & 7, ng = lane >> 3;
    float vacc[4][8];
#pragma unroll
    for (int jj = 0; jj < 4; ++jj)
#pragma unroll
        for (int k = 0; k < 8; ++k) vacc[jj][k] = 0.f;
#pragma unroll
    for (int lrel = 0; lrel < 16; ++lrel) {
        const int row = lw + lrel;
        float4 cv = c4[row * 9 + ng];
        const float4* up = uS4 + row * 17 + dr * 2;
        float4 u0 = up[0], u1 = up[1];
        const float* cp = (const float*)&cv;
#pragma unroll
        for (int jj = 0; jj < 4; ++jj) {
            float c = cp[jj];
            vacc[jj][0] = fmaf(c, u0.x, vacc[jj][0]);
            vacc[jj][1] = fmaf(c, u0.y, vacc[jj][1]);
            vacc[jj][2] = fmaf(c, u0.z, vacc[jj][2]);
            vacc[jj][3] = fmaf(c, u0.w, vacc[jj][3]);
            vacc[jj][4] = fmaf(c, u1.x, vacc[jj][4]);
            vacc[jj][5] = fmaf(c, u1.y, vacc[jj][5]);
            vacc[jj][6] = fmaf(c, u1.z, vacc[jj][6]);
            vacc[jj][7] = fmaf(c, u1.w, vacc[jj][7]);
        }
    }
    __syncthreads();                   // all uS/c reads done -> overlay red

    // ---- fold 8 wave-partials: odd waves write, even waves add, 4->1 ----
    float* red = smem;                 // [4][2048]
    const int p = w >> 1;
    if (w & 1) {
#pragma unroll
        for (int jj = 0; jj < 4; ++jj) {
            float4* rp = (float4*)(red + p * 2048 + (ng * 4 + jj) * 64 + dr * 8);
            float4 r0 = {vacc[jj][0], vacc[jj][1], vacc[jj][2], vacc[jj][3]};
            float4 r1 = {vacc[jj][4], vacc[jj][5], vacc[jj][6], vacc[jj][7]};
            rp[0] = r0;
            rp[1] = r1;
        }
    }
    __syncthreads();
    if (!(w & 1)) {
#pragma unroll
        for (int jj = 0; jj < 4; ++jj) {
            float4* rp = (float4*)(red + p * 2048 + (ng * 4 + jj) * 64 + dr * 8);
            float4 r0 = rp[0], r1 = rp[1];
            r0.x += vacc[jj][0]; r0.y += vacc[jj][1];
            r0.z += vacc[jj][2]; r0.w += vacc[jj][3];
            r1.x += vacc[jj][4]; r1.y += vacc[jj][5];
            r1.z += vacc[jj][6]; r1.w += vacc[jj][7];
            rp[0] = r0;
            rp[1] = r1;
        }
    }
    __syncthreads();
    {
        float4* red4 = (float4*)red;
        float4 a0 = red4[t], a1 = red4[512 + t];
        float4 a2 = red4[1024 + t], a3 = red4[1536 + t];
        float4 o = {a0.x + a1.x + a2.x + a3.x, a0.y + a1.y + a2.y + a3.y,
                    a0.z + a1.z + a2.z + a3.z, a0.w + a1.w + a2.w + a3.w};
        float* vp = vout + b * 2048 + t * 4;
        atomicAdd(vp + 0, o.x);
        atomicAdd(vp + 1, o.y);
        atomicAdd(vp + 2, o.z);
        atomicAdd(vp + 3, o.w);
    }
}

// ---------------------------------------------------------------------------
// Final caps: grid 32 (one block per b), 512 threads.
// ---------------------------------------------------------------------------
__global__ __launch_bounds__(512) void k_caps_final(const float* __restrict__ W,
                                                    const float* __restrict__ vin,
                                                    float* __restrict__ out) {
    __shared__ float cSf[2688];
    caps_head<0, 1>((int)blockIdx.x, (int)threadIdx.x, W, vin, nullptr, out, cSf);
}

extern "C" void kernel_launch(void* const* d_in, const int* in_sizes, int n_in,
                              void* d_out, int out_size, void* d_ws, size_t ws_size,
                              hipStream_t stream) {
    const float* u = (const float*)d_in[0];  // [32, 2048, 64] f32
    const float* W = (const float*)d_in[1];  // [1, 64, 512]  f32
    float* out = (float*)d_out;              // [32, 32, 16]  f32
    float* ws  = (float*)d_ws;
    float* v0 = ws;                          // 32*64    = 2048 floats
    float* v1 = ws + 2048;                   // 32*2048  = 65536 floats
    float* v2 = ws + 2048 + 65536;           // 32*2048  = 65536 floats

    hipMemsetAsync(ws, 0, (2048 + 65536 + 65536) * sizeof(float), stream);

    k_sum<<<512, 256, 0, stream>>>(u, v0);
    k_route<1><<<512, 512, 0, stream>>>(u, W, v0, v1);
    k_route<0><<<512, 512, 0, stream>>>(u, W, v1, v2);
    k_caps_final<<<32, 512, 0, stream>>>(W, v2, out);
}